// Round 6
// baseline (289.160 us; speedup 1.0000x reference)
//
#include <hip/hip_runtime.h>
#include <stdint.h>

typedef __bf16 bf16x8_t __attribute__((ext_vector_type(8)));
typedef float f32x4_t __attribute__((ext_vector_type(4)));

__device__ __forceinline__ uint32_t f32_to_bf16_bits(float f) {
    union { float f; uint32_t u; } v; v.f = f;
    return (v.u + 0x7FFFu + ((v.u >> 16) & 1u)) >> 16;   // RNE, finite inputs
}

__device__ __forceinline__ float bf16_bits_to_f32(uint32_t b) {
    union { uint32_t u; float f; } v; v.u = b << 16;
    return v.f;
}

// ---------------------------------------------------------------------------
// Merged prep (unchanged)
// ---------------------------------------------------------------------------
__global__ void prep_kernel(const float* __restrict__ X,
                            unsigned short* __restrict__ Ae,
                            unsigned short* __restrict__ Ao,
                            unsigned short* __restrict__ Xe,
                            unsigned short* __restrict__ Xo) {
    if (blockIdx.x < 4096) {
        const int idx = blockIdx.x * 256 + threadIdx.x;   // 0..1M-1
        const int sel = idx >> 19;                        // 0=even, 1=odd matrix
        const int e   = idx & ((1 << 19) - 1);
        const int n   = e >> 8;                           // 0..2047
        const int c0  = (e & 255) << 3;                   // col start
        const uint32_t tn = (uint32_t)(2 * n + 1);
        unsigned short* dst = sel ? Ao : Ae;
        uint32_t packed[4];
#pragma unroll
        for (int jj = 0; jj < 4; ++jj) {
            uint32_t cA = (uint32_t)(c0 + 2 * jj);
            uint32_t cB = cA + 1;
            uint32_t r0 = ((2u * cA + (uint32_t)sel) * tn) & 16383u;
            uint32_t r1 = ((2u * cB + (uint32_t)sel) * tn) & 16383u;
            float v0 = __cosf((float)r0 * 3.8349519697141e-4f);   // pi/8192
            float v1 = __cosf((float)r1 * 3.8349519697141e-4f);
            packed[jj] = f32_to_bf16_bits(v0) | (f32_to_bf16_bits(v1) << 16);
        }
        *(uint4*)(dst + (size_t)n * 2048 + c0) = make_uint4(packed[0], packed[1], packed[2], packed[3]);
    } else {
        const int idx = (blockIdx.x - 4096) * 256 + threadIdx.x;   // 0..2M-1
        const int q   = idx >> 9;
        const int p0  = (idx & 511) << 3;
        const float4* src = (const float4*)(X + (size_t)q * 4096 + p0);
        float4 a = src[0];
        float4 b = src[1];
        uint2 ev, od;
        ev.x = f32_to_bf16_bits(a.x) | (f32_to_bf16_bits(a.z) << 16);
        ev.y = f32_to_bf16_bits(b.x) | (f32_to_bf16_bits(b.z) << 16);
        od.x = f32_to_bf16_bits(a.y) | (f32_to_bf16_bits(a.w) << 16);
        od.y = f32_to_bf16_bits(b.y) | (f32_to_bf16_bits(b.w) << 16);
        *(uint2*)(Xe + (size_t)q * 2048 + (p0 >> 1)) = ev;
        *(uint2*)(Xo + (size_t)q * 2048 + (p0 >> 1)) = od;
    }
}

// ---------------------------------------------------------------------------
// Single-parity 128x256 GEMM, BK=32, 256 threads = 4 waves (1M x 4N),
// per-wave 128x64, 2 blocks/CU (48 KB LDS, ~116 VGPR + 128 AGPR).
//
// Round-6 change (single variable): CORRECTED LDS swizzle. At 4 slots/row a
// row spans only half the banks and the old sw=(r&3) XOR has period 4 against
// the period-2 bank offset 16r mod 32 -> 16 fragment rows hit only 4 bank-
// quads = 4-way conflict (measured 6.29M conflicts, round 5). New swizzle
// sw(r) = (r ^ (r>>2)) & 3 spreads the 16 rows over 8 bank-quads x2 = 2-way,
// which is free (m136). sw is invariant under r -> r+16 (16 = 0 mod 4 in both
// terms), so per-lane sw is constant across the fragment i/j loops.
//
// Schedule: proven 2-phase loop — STAGE(t+1) first, compute tile t, one
// vmcnt(0)+s_barrier per K-tile. Staging pre-swizzles the global source
// (global_load_lds dest stays lane-linear); fragment reads XOR the slot.
// ---------------------------------------------------------------------------
#define GLL(gp, lp) __builtin_amdgcn_global_load_lds( \
        (const __attribute__((address_space(1))) uint32_t*)(gp), \
        (__attribute__((address_space(3))) uint32_t*)(lp), 16, 0, 0)

__global__ __launch_bounds__(256, 2)
void gemm128_kernel(const unsigned short* __restrict__ Ae,
                    const unsigned short* __restrict__ Ao,
                    const unsigned short* __restrict__ Be,
                    const unsigned short* __restrict__ Bo,
                    unsigned short* __restrict__ Ce,
                    unsigned short* __restrict__ Co) {
    constexpr int KD = 2048;
    // 2 buffers x (A 128x32 + B 256x32 bf16) = 2 x 12288 shorts = 48 KB
    __shared__ __attribute__((aligned(16))) unsigned short smem[2 * 12288];

    const int tid  = threadIdx.x;
    const int wave = tid >> 6;     // wn 0..3 (N: data dim, 64 cols each)
    const int lane = tid & 63;

    // Bijective XCD swizzle (512 wgs = 8 XCDs x 64), y-major chunks.
    const int bid = blockIdx.x;
    const int wg  = (bid & 7) * 64 + (bid >> 3);
    const int par = wg >> 8;              // parity
    const int ty  = (wg >> 4) & 15;       // m-tile
    const int tx  = wg & 15;              // c-tile
    const int tile_m = ty << 7;           // cosine rows: [0,2048)
    const int tile_c = tx << 8;           // data rows (= C cols): [0,4096)

    const unsigned short* gA = (par ? Ao : Ae) + (size_t)tile_m * KD;
    const unsigned short* gB = (par ? Bo : Be) + (size_t)tile_c * KD;
    unsigned short*       gC = par ? Co : Ce;

    f32x4_t acc[8][4];
#pragma unroll
    for (int i = 0; i < 8; ++i)
#pragma unroll
        for (int j = 0; j < 4; ++j)
            acc[i][j] = (f32x4_t){0.f, 0.f, 0.f, 0.f};

    // Staging: A = 512 chunks of 16B (128 rows x 4 slots), B = 1024 chunks
    // (256 rows x 4 slots). Thread handles chunks c = tid + 256k.
    // Phys slot s = c&3 of row = c>>2 holds logical chunk g = s ^ sw(row),
    // sw(row) = (row ^ (row>>2)) & 3  -> fetch global chunk g, linear dest.
    int a_src[2], a_lds[2], b_src[4], b_lds[4];
#pragma unroll
    for (int k = 0; k < 2; ++k) {
        const int c   = tid + (k << 8);
        const int row = c >> 2;
        const int g   = (c & 3) ^ ((row ^ (row >> 2)) & 3);
        a_src[k] = row * KD + (g << 3);
        a_lds[k] = c << 3;                  // shorts, A region [0,4096)
    }
#pragma unroll
    for (int k = 0; k < 4; ++k) {
        const int c   = tid + (k << 8);
        const int row = c >> 2;
        const int g   = (c & 3) ^ ((row ^ (row >> 2)) & 3);
        b_src[k] = row * KD + (g << 3);
        b_lds[k] = 4096 + (c << 3);         // shorts, B region [4096,12288)
    }

    // Fragment read addressing (swizzled). Rows read: frow + 16*i (A),
    // wave*64 + frow + 16*j (B); both have sw(r) = (frow ^ (frow>>2)) & 3.
    const int frow = lane & 15;
    const int sw3  = (frow ^ (frow >> 2)) & 3;
    const int gq   = lane >> 4;             // k-chunk 0..3 (K=32 = 4 chunks)
    const int aRow = frow * 32;                          // A LDS [128][32]
    const int bRow = 4096 + (wave * 64 + frow) * 32;     // B LDS [256][32]

#define STAGE_TILE(buf, kadv) do {                                            \
    GLL(gA + (kadv) + a_src[0], (buf) + a_lds[0]);                            \
    GLL(gA + (kadv) + a_src[1], (buf) + a_lds[1]);                            \
    GLL(gB + (kadv) + b_src[0], (buf) + b_lds[0]);                            \
    GLL(gB + (kadv) + b_src[1], (buf) + b_lds[1]);                            \
    GLL(gB + (kadv) + b_src[2], (buf) + b_lds[2]);                            \
    GLL(gB + (kadv) + b_src[3], (buf) + b_lds[3]);                            \
} while (0)

#define COMPUTE_TILE(buf) do {                                                \
    const int so_ = (gq ^ sw3) << 3;                                          \
    bf16x8_t af_[8], bf_[4];                                                  \
    _Pragma("unroll")                                                         \
    for (int i_ = 0; i_ < 8; ++i_) af_[i_] = *(const bf16x8_t*)((buf) + aRow + i_ * 512 + so_); \
    _Pragma("unroll")                                                         \
    for (int j_ = 0; j_ < 4; ++j_) bf_[j_] = *(const bf16x8_t*)((buf) + bRow + j_ * 512 + so_); \
    __builtin_amdgcn_s_setprio(1);                                            \
    _Pragma("unroll")                                                         \
    for (int i_ = 0; i_ < 8; ++i_)                                            \
        _Pragma("unroll")                                                     \
        for (int j_ = 0; j_ < 4; ++j_)                                        \
            acc[i_][j_] = __builtin_amdgcn_mfma_f32_16x16x32_bf16(af_[i_], bf_[j_], acc[i_][j_], 0, 0, 0); \
    __builtin_amdgcn_s_setprio(0);                                            \
} while (0)

#define TILE_SYNC() do {                                                      \
    asm volatile("s_waitcnt vmcnt(0)" ::: "memory");                          \
    __builtin_amdgcn_s_barrier();                                             \
    asm volatile("" ::: "memory");                                            \
} while (0)

    // Prologue: stage K-tile 0 into buf0.
    STAGE_TILE(smem, 0);
    TILE_SYNC();

    int co = 0;   // compute-buffer offset (shorts); staging targets co^12288
#pragma unroll 1
    for (int t = 0; t < 63; ++t) {
        STAGE_TILE(smem + (co ^ 12288), (t + 1) << 5);
        COMPUTE_TILE(smem + co);
        TILE_SYNC();
        co ^= 12288;
    }
    COMPUTE_TILE(smem + co);   // K-tile 63: nothing left to stage

#undef STAGE_TILE
#undef COMPUTE_TILE
#undef TILE_SYNC

    // C/D map: col = lane&15 (data dim), row = (lane>>4)*4 + reg (cos dim)
    const int orow = tile_m + ((lane >> 4) << 2);
    const int ocol = tile_c + wave * 64 + (lane & 15);
#pragma unroll
    for (int i = 0; i < 8; ++i)
#pragma unroll
        for (int j = 0; j < 4; ++j)
#pragma unroll
            for (int r = 0; r < 4; ++r) {
                const int m = orow + i * 16 + r;
                const int w = ocol + j * 16;
                gC[(size_t)m * 4096 + w] = (unsigned short)f32_to_bf16_bits(acc[i][j][r]);
            }
}

// ---------------------------------------------------------------------------
// Butterfly 1: Ce,Co [2048][4096] bf16 -> Te,To [4096][2048] bf16. (unchanged)
// ---------------------------------------------------------------------------
__global__ void bfly1_kernel(const unsigned short* __restrict__ Ce,
                             const unsigned short* __restrict__ Co,
                             unsigned short* __restrict__ Te,
                             unsigned short* __restrict__ To) {
    const int m  = blockIdx.x;
    const int c0 = threadIdx.x << 4;
    const uint4 e0 = *(const uint4*)(Ce + (size_t)m * 4096 + c0);
    const uint4 e1 = *(const uint4*)(Ce + (size_t)m * 4096 + c0 + 8);
    const uint4 o0 = *(const uint4*)(Co + (size_t)m * 4096 + c0);
    const uint4 o1 = *(const uint4*)(Co + (size_t)m * 4096 + c0 + 8);
    const uint32_t eu[8] = {e0.x, e0.y, e0.z, e0.w, e1.x, e1.y, e1.z, e1.w};
    const uint32_t ou[8] = {o0.x, o0.y, o0.z, o0.w, o1.x, o1.y, o1.z, o1.w};
    uint32_t se[4], so_[4], de[4], do_[4];
#pragma unroll
    for (int u = 0; u < 4; ++u) {
        float eA = bf16_bits_to_f32(eu[2*u] & 0xFFFF),  oA = bf16_bits_to_f32(ou[2*u] & 0xFFFF);
        float eB = bf16_bits_to_f32(eu[2*u] >> 16),     oB = bf16_bits_to_f32(ou[2*u] >> 16);
        float eC = bf16_bits_to_f32(eu[2*u+1] & 0xFFFF),oC = bf16_bits_to_f32(ou[2*u+1] & 0xFFFF);
        float eD = bf16_bits_to_f32(eu[2*u+1] >> 16),   oD = bf16_bits_to_f32(ou[2*u+1] >> 16);
        se[u]  = f32_to_bf16_bits(eA + oA) | (f32_to_bf16_bits(eC + oC) << 16);
        so_[u] = f32_to_bf16_bits(eB + oB) | (f32_to_bf16_bits(eD + oD) << 16);
        de[u]  = f32_to_bf16_bits(eA - oA) | (f32_to_bf16_bits(eC - oC) << 16);
        do_[u] = f32_to_bf16_bits(eB - oB) | (f32_to_bf16_bits(eD - oD) << 16);
    }
    const size_t rs = (size_t)m * 2048 + (c0 >> 1);
    const size_t rd = (size_t)(4095 - m) * 2048 + (c0 >> 1);
    *(uint4*)(Te + rs) = make_uint4(se[0], se[1], se[2], se[3]);
    *(uint4*)(To + rs) = make_uint4(so_[0], so_[1], so_[2], so_[3]);
    *(uint4*)(Te + rd) = make_uint4(de[0], de[1], de[2], de[3]);
    *(uint4*)(To + rd) = make_uint4(do_[0], do_[1], do_[2], do_[3]);
}

// ---------------------------------------------------------------------------
// Butterfly 2: Ce2,Co2 [2048][4096] bf16 -> out [4096][4096] f32. (unchanged)
// ---------------------------------------------------------------------------
__global__ void bfly2_kernel(const unsigned short* __restrict__ Ce,
                             const unsigned short* __restrict__ Co,
                             float* __restrict__ out) {
    const int m  = blockIdx.x;
    const int c0 = threadIdx.x << 4;
    const uint4 e0 = *(const uint4*)(Ce + (size_t)m * 4096 + c0);
    const uint4 e1 = *(const uint4*)(Ce + (size_t)m * 4096 + c0 + 8);
    const uint4 o0 = *(const uint4*)(Co + (size_t)m * 4096 + c0);
    const uint4 o1 = *(const uint4*)(Co + (size_t)m * 4096 + c0 + 8);
    const uint32_t eu[8] = {e0.x, e0.y, e0.z, e0.w, e1.x, e1.y, e1.z, e1.w};
    const uint32_t ou[8] = {o0.x, o0.y, o0.z, o0.w, o1.x, o1.y, o1.z, o1.w};
    float s[16], d[16];
#pragma unroll
    for (int u = 0; u < 8; ++u) {
        const float eL = bf16_bits_to_f32(eu[u] & 0xFFFF), oL = bf16_bits_to_f32(ou[u] & 0xFFFF);
        const float eH = bf16_bits_to_f32(eu[u] >> 16),    oH = bf16_bits_to_f32(ou[u] >> 16);
        s[2*u] = eL + oL; s[2*u+1] = eH + oH;
        d[2*u] = eL - oL; d[2*u+1] = eH - oH;
    }
    float* ps = out + (size_t)m * 4096 + c0;
    float* pd = out + (size_t)(4095 - m) * 4096 + c0;
#pragma unroll
    for (int u = 0; u < 4; ++u) {
        *(float4*)(ps + 4 * u) = make_float4(s[4*u], s[4*u+1], s[4*u+2], s[4*u+3]);
        *(float4*)(pd + 4 * u) = make_float4(d[4*u], d[4*u+1], d[4*u+2], d[4*u+3]);
    }
}

// ---------------------------------------------------------------------------
// Pipeline (unchanged structure):
//   prep -> gemm1 (parity in swizzled wg id) -> bfly1 -> gemm2 -> bfly2
// ws (80 MB): Ae[0,8) Ao[8,16) | Xe[16,32) Xo[32,48) (reused as Te,To)
//             | C1e[48,64) C1o[64,80) (reused as C2e,C2o)
// ---------------------------------------------------------------------------
extern "C" void kernel_launch(void* const* d_in, const int* in_sizes, int n_in,
                              void* d_out, int out_size, void* d_ws, size_t ws_size,
                              hipStream_t stream) {
    const float* x = (const float*)d_in[0];
    char* ws = (char*)d_ws;
    const size_t MB = 1024 * 1024;
    unsigned short* Ae = (unsigned short*)(ws);
    unsigned short* Ao = (unsigned short*)(ws + 8 * MB);
    unsigned short* Xe = (unsigned short*)(ws + 16 * MB);   // later Te
    unsigned short* Xo = (unsigned short*)(ws + 32 * MB);   // later To
    unsigned short* C1e = (unsigned short*)(ws + 48 * MB);  // later C2e
    unsigned short* C1o = (unsigned short*)(ws + 64 * MB);  // later C2o
    float* out = (float*)d_out;

    prep_kernel<<<12288, 256, 0, stream>>>(x, Ae, Ao, Xe, Xo);

    gemm128_kernel<<<512, 256, 0, stream>>>(Ae, Ao, Xe, Xo, C1e, C1o);
    bfly1_kernel<<<2048, 256, 0, stream>>>(C1e, C1o, /*Te=*/Xe, /*To=*/Xo);
    gemm128_kernel<<<512, 256, 0, stream>>>(Ae, Ao, /*Te=*/Xe, /*To=*/Xo, C1e, C1o);
    bfly2_kernel<<<2048, 256, 0, stream>>>(C1e, C1o, out);
}

// Round 7
// 262.425 us; speedup vs baseline: 1.1019x; 1.1019x over previous
//
#include <hip/hip_runtime.h>
#include <stdint.h>

typedef __bf16 bf16x8_t __attribute__((ext_vector_type(8)));
typedef float f32x4_t __attribute__((ext_vector_type(4)));

__device__ __forceinline__ uint32_t f32_to_bf16_bits(float f) {
    union { float f; uint32_t u; } v; v.f = f;
    return (v.u + 0x7FFFu + ((v.u >> 16) & 1u)) >> 16;   // RNE, finite inputs
}

__device__ __forceinline__ float bf16_bits_to_f32(uint32_t b) {
    union { uint32_t u; float f; } v; v.u = b << 16;
    return v.f;
}

// ---------------------------------------------------------------------------
// Merged prep (unchanged)
// ---------------------------------------------------------------------------
__global__ void prep_kernel(const float* __restrict__ X,
                            unsigned short* __restrict__ Ae,
                            unsigned short* __restrict__ Ao,
                            unsigned short* __restrict__ Xe,
                            unsigned short* __restrict__ Xo) {
    if (blockIdx.x < 4096) {
        const int idx = blockIdx.x * 256 + threadIdx.x;   // 0..1M-1
        const int sel = idx >> 19;                        // 0=even, 1=odd matrix
        const int e   = idx & ((1 << 19) - 1);
        const int n   = e >> 8;                           // 0..2047
        const int c0  = (e & 255) << 3;                   // col start
        const uint32_t tn = (uint32_t)(2 * n + 1);
        unsigned short* dst = sel ? Ao : Ae;
        uint32_t packed[4];
#pragma unroll
        for (int jj = 0; jj < 4; ++jj) {
            uint32_t cA = (uint32_t)(c0 + 2 * jj);
            uint32_t cB = cA + 1;
            uint32_t r0 = ((2u * cA + (uint32_t)sel) * tn) & 16383u;
            uint32_t r1 = ((2u * cB + (uint32_t)sel) * tn) & 16383u;
            float v0 = __cosf((float)r0 * 3.8349519697141e-4f);   // pi/8192
            float v1 = __cosf((float)r1 * 3.8349519697141e-4f);
            packed[jj] = f32_to_bf16_bits(v0) | (f32_to_bf16_bits(v1) << 16);
        }
        *(uint4*)(dst + (size_t)n * 2048 + c0) = make_uint4(packed[0], packed[1], packed[2], packed[3]);
    } else {
        const int idx = (blockIdx.x - 4096) * 256 + threadIdx.x;   // 0..2M-1
        const int q   = idx >> 9;
        const int p0  = (idx & 511) << 3;
        const float4* src = (const float4*)(X + (size_t)q * 4096 + p0);
        float4 a = src[0];
        float4 b = src[1];
        uint2 ev, od;
        ev.x = f32_to_bf16_bits(a.x) | (f32_to_bf16_bits(a.z) << 16);
        ev.y = f32_to_bf16_bits(b.x) | (f32_to_bf16_bits(b.z) << 16);
        od.x = f32_to_bf16_bits(a.y) | (f32_to_bf16_bits(a.w) << 16);
        od.y = f32_to_bf16_bits(b.y) | (f32_to_bf16_bits(b.w) << 16);
        *(uint2*)(Xe + (size_t)q * 2048 + (p0 >> 1)) = ev;
        *(uint2*)(Xo + (size_t)q * 2048 + (p0 >> 1)) = od;
    }
}

// ---------------------------------------------------------------------------
// Single-parity 256x256 GEMM, BK=64, 8 waves (2M x 4N), per-wave 128x64.
// 8-phase counted-vmcnt schedule — round-7 change vs round 4 (single
// mechanism): REMOVED the per-phase `s_waitcnt lgkmcnt(0)` asm and
// `sched_barrier(0)`. Those pinned the compiler's scheduler into lockstep
// (m141 failure mode, −40%); the ds_read->MFMA dependencies are C-level, so
// the compiler inserts fine-grained lgkmcnt(N) itself (m97). Correctness:
// every ds_read is consumed by an MFMA within its own phase, so compiler
// lgkm waits drain it before the closing barrier; staging overwrites are
// >=1 barrier later (same verified map as round 4). Counted vmcnt(4) at
// phases 1,4,5,8 unchanged (never drains to 0 in the main loop).
//
// LDS: buf0 (even tiles) / buf1 (odd tiles), each A[256][64]+B[256][64],
// 128 KB total, chunk-XOR swizzle (phys slot s of row r holds k-chunk
// s^(r&7); staging pre-swizzles the global src; reads XOR the slot) — 0
// bank conflicts (verified rounds 0-4).
// ---------------------------------------------------------------------------
#define GLL(gp, lp) __builtin_amdgcn_global_load_lds( \
        (const __attribute__((address_space(1))) uint32_t*)(gp), \
        (__attribute__((address_space(3))) uint32_t*)(lp), 16, 0, 0)

__global__ __launch_bounds__(512, 2)
void gemm256_kernel(const unsigned short* __restrict__ Ae,
                    const unsigned short* __restrict__ Ao,
                    const unsigned short* __restrict__ Be,
                    const unsigned short* __restrict__ Bo,
                    unsigned short* __restrict__ Ce,
                    unsigned short* __restrict__ Co) {
    constexpr int KD = 2048;
    __shared__ __attribute__((aligned(16))) unsigned short smem[2 * 32768];

    const int tid  = threadIdx.x;
    const int wave = tid >> 6;
    const int lane = tid & 63;
    const int wm   = wave >> 2;     // 0..1 (M: cosine dim, 128 rows each)
    const int wn   = wave & 3;      // 0..3 (N: data dim, 64 cols each)

    const int tile_m = blockIdx.y << 8;   // cosine rows: [0,2048)
    const int tile_c = blockIdx.x << 8;   // data rows (= C cols): [0,4096)
    const int par    = blockIdx.z;

    const unsigned short* gA = (par ? Ao : Ae) + (size_t)tile_m * KD;
    const unsigned short* gB = (par ? Bo : Be) + (size_t)tile_c * KD;
    unsigned short*       gC = par ? Co : Ce;

    f32x4_t acc[8][4];
#pragma unroll
    for (int i = 0; i < 8; ++i)
#pragma unroll
        for (int j = 0; j < 4; ++j)
            acc[i][j] = (f32x4_t){0.f, 0.f, 0.f, 0.f};

    // Staging: panel = 2048 chunks of 16B over 256 rows x 8 slots.
    // Stage-chunk k covers rows [64k, 64k+64); thread handles chunk c=tid+512k.
    //   per-lane global src (swizzled): row = c>>3, g = (c&7)^(row&7)
    int src_off[4], lds_off[4];
#pragma unroll
    for (int k = 0; k < 4; ++k) {
        const int c   = tid + (k << 9);
        const int row = c >> 3;
        const int g   = (c & 7) ^ (row & 7);
        src_off[k] = row * KD + (g << 3);
        lds_off[k] = c << 3;   // shorts
    }

    // Fragment read addressing (swizzled).
    const int frow = lane & 15;
    const int sw   = frow & 7;
    const int gq   = lane >> 4;
    const int aRowB = (wm * 128 + frow) * 64;   // A LDS [256][64] shorts
    const int bRowB = (wn * 64  + frow) * 64;   // B LDS [256][64] shorts

// stage units: 2 GLL each. Ah0 = chunks {0,2}, Ah1 = {1,3} (A rows read by
// mh=0 / mh=1 phases); B01 = chunks {0,1} (waves wn 0,1), B23 = {2,3}.
#define S_A0(b, kadv)  do { GLL(gA + (kadv) + src_off[0], (b) + lds_off[0]); \
                            GLL(gA + (kadv) + src_off[2], (b) + lds_off[2]); } while (0)
#define S_A1(b, kadv)  do { GLL(gA + (kadv) + src_off[1], (b) + lds_off[1]); \
                            GLL(gA + (kadv) + src_off[3], (b) + lds_off[3]); } while (0)
#define S_B01(b, kadv) do { GLL(gB + (kadv) + src_off[0], (b) + 16384 + lds_off[0]); \
                            GLL(gB + (kadv) + src_off[1], (b) + 16384 + lds_off[1]); } while (0)
#define S_B23(b, kadv) do { GLL(gB + (kadv) + src_off[2], (b) + 16384 + lds_off[2]); \
                            GLL(gB + (kadv) + src_off[3], (b) + 16384 + lds_off[3]); } while (0)
#define S_NONE ((void)0)

    bf16x8_t bfr[4];   // B fragments: loaded in mh=0 phases, reused in mh=1

#define PHASE(cb, mh, kh, LOADB, STAGE_STMT, VM) do {                          \
    const int so_ = ((((kh) << 2) + gq) ^ sw) << 3;                            \
    bf16x8_t af_[4];                                                           \
    _Pragma("unroll")                                                          \
    for (int i_ = 0; i_ < 4; ++i_)                                             \
        af_[i_] = *(const bf16x8_t*)((cb) + aRowB + ((mh) * 4 + i_) * 1024 + so_); \
    if (LOADB) {                                                               \
        _Pragma("unroll")                                                      \
        for (int j_ = 0; j_ < 4; ++j_)                                         \
            bfr[j_] = *(const bf16x8_t*)((cb) + 16384 + bRowB + j_ * 1024 + so_); \
    }                                                                          \
    STAGE_STMT;                                                                \
    asm volatile("" ::: "memory");                                             \
    __builtin_amdgcn_s_barrier();                                              \
    asm volatile("" ::: "memory");                                             \
    __builtin_amdgcn_s_setprio(1);                                             \
    _Pragma("unroll")                                                          \
    for (int i_ = 0; i_ < 4; ++i_)                                             \
        _Pragma("unroll")                                                      \
        for (int j_ = 0; j_ < 4; ++j_)                                         \
            acc[(mh) * 4 + i_][j_] = __builtin_amdgcn_mfma_f32_16x16x32_bf16(  \
                af_[i_], bfr[j_], acc[(mh) * 4 + i_][j_], 0, 0, 0);            \
    __builtin_amdgcn_s_setprio(0);                                             \
    if constexpr ((VM) == 4) asm volatile("s_waitcnt vmcnt(4)" ::: "memory");  \
    else if constexpr ((VM) == 2) asm volatile("s_waitcnt vmcnt(2)" ::: "memory"); \
    else if constexpr ((VM) == 0) asm volatile("s_waitcnt vmcnt(0)" ::: "memory"); \
    asm volatile("" ::: "memory");                                             \
    __builtin_amdgcn_s_barrier();                                              \
    asm volatile("" ::: "memory");                                             \
} while (0)

// iter J: compute tile 2J (buf0, ph1-4) and 2J+1 (buf1, ph5-8);
// stage (2J+1).B/Ah1 into buf1 (ph1-3), tile 2J+2 into buf0 (ph4-7),
// (2J+3).Ah0 into buf1 (ph8). Waits vmcnt(4) at ph1,4,5,8 (derived).
#define ITER_FULL(J) do {                                                      \
    unsigned short* b0_ = smem;                                                \
    unsigned short* b1_ = smem + 32768;                                        \
    const int k1_ = (2 * (J) + 1) << 6;                                        \
    const int k2_ = (2 * (J) + 2) << 6;                                        \
    const int k3_ = (2 * (J) + 3) << 6;                                        \
    PHASE(b0_, 0, 0, 1, S_B01(b1_, k1_), 4);                                   \
    PHASE(b0_, 1, 0, 0, S_B23(b1_, k1_), -1);                                  \
    PHASE(b0_, 0, 1, 1, S_A1 (b1_, k1_), -1);                                  \
    PHASE(b0_, 1, 1, 0, S_A0 (b0_, k2_), 4);                                   \
    PHASE(b1_, 0, 0, 1, S_B01(b0_, k2_), 4);                                   \
    PHASE(b1_, 1, 0, 0, S_B23(b0_, k2_), -1);                                  \
    PHASE(b1_, 0, 1, 1, S_A1 (b0_, k2_), -1);                                  \
    PHASE(b1_, 1, 1, 0, S_A0 (b1_, k3_), 4);                                   \
} while (0)

// tail (J=15, tiles 30,31): finish staging tile 31 (ph1-3), then drain.
#define ITER_TAIL() do {                                                       \
    unsigned short* b0_ = smem;                                                \
    unsigned short* b1_ = smem + 32768;                                        \
    const int k1_ = 31 << 6;                                                   \
    PHASE(b0_, 0, 0, 1, S_B01(b1_, k1_), 4);                                   \
    PHASE(b0_, 1, 0, 0, S_B23(b1_, k1_), -1);                                  \
    PHASE(b0_, 0, 1, 1, S_A1 (b1_, k1_), -1);                                  \
    PHASE(b0_, 1, 1, 0, S_NONE, 2);                                            \
    PHASE(b1_, 0, 0, 1, S_NONE, 0);                                            \
    PHASE(b1_, 1, 0, 0, S_NONE, -1);                                           \
    PHASE(b1_, 0, 1, 1, S_NONE, -1);                                           \
    PHASE(b1_, 1, 1, 0, S_NONE, -1);                                           \
} while (0)

    // Prologue: tile 0 complete (8 GLL) + tile 1's Ah0 (2 GLL); allow the
    // latter to stay in flight across the first barrier.
    S_A0(smem, 0); S_A1(smem, 0); S_B01(smem, 0); S_B23(smem, 0);
    S_A0(smem + 32768, 64);
    asm volatile("s_waitcnt vmcnt(2)" ::: "memory");
    __builtin_amdgcn_s_barrier();
    asm volatile("" ::: "memory");

#pragma unroll 1
    for (int J = 0; J < 15; ++J) ITER_FULL(J);
    ITER_TAIL();

#undef ITER_TAIL
#undef ITER_FULL
#undef PHASE
#undef S_NONE
#undef S_B23
#undef S_B01
#undef S_A1
#undef S_A0

    // C/D map: col = lane&15 (data dim), row = (lane>>4)*4 + reg (cos dim)
    const int orow = tile_m + wm * 128 + ((lane >> 4) << 2);
    const int ocol = tile_c + wn * 64 + (lane & 15);
#pragma unroll
    for (int i = 0; i < 8; ++i)
#pragma unroll
        for (int j = 0; j < 4; ++j)
#pragma unroll
            for (int r = 0; r < 4; ++r) {
                const int m = orow + i * 16 + r;
                const int w = ocol + j * 16;
                gC[(size_t)m * 4096 + w] = (unsigned short)f32_to_bf16_bits(acc[i][j][r]);
            }
}

// ---------------------------------------------------------------------------
// Butterfly 1: Ce,Co [2048][4096] bf16 -> Te,To [4096][2048] bf16. (unchanged)
// ---------------------------------------------------------------------------
__global__ void bfly1_kernel(const unsigned short* __restrict__ Ce,
                             const unsigned short* __restrict__ Co,
                             unsigned short* __restrict__ Te,
                             unsigned short* __restrict__ To) {
    const int m  = blockIdx.x;
    const int c0 = threadIdx.x << 4;
    const uint4 e0 = *(const uint4*)(Ce + (size_t)m * 4096 + c0);
    const uint4 e1 = *(const uint4*)(Ce + (size_t)m * 4096 + c0 + 8);
    const uint4 o0 = *(const uint4*)(Co + (size_t)m * 4096 + c0);
    const uint4 o1 = *(const uint4*)(Co + (size_t)m * 4096 + c0 + 8);
    const uint32_t eu[8] = {e0.x, e0.y, e0.z, e0.w, e1.x, e1.y, e1.z, e1.w};
    const uint32_t ou[8] = {o0.x, o0.y, o0.z, o0.w, o1.x, o1.y, o1.z, o1.w};
    uint32_t se[4], so_[4], de[4], do_[4];
#pragma unroll
    for (int u = 0; u < 4; ++u) {
        float eA = bf16_bits_to_f32(eu[2*u] & 0xFFFF),  oA = bf16_bits_to_f32(ou[2*u] & 0xFFFF);
        float eB = bf16_bits_to_f32(eu[2*u] >> 16),     oB = bf16_bits_to_f32(ou[2*u] >> 16);
        float eC = bf16_bits_to_f32(eu[2*u+1] & 0xFFFF),oC = bf16_bits_to_f32(ou[2*u+1] & 0xFFFF);
        float eD = bf16_bits_to_f32(eu[2*u+1] >> 16),   oD = bf16_bits_to_f32(ou[2*u+1] >> 16);
        se[u]  = f32_to_bf16_bits(eA + oA) | (f32_to_bf16_bits(eC + oC) << 16);
        so_[u] = f32_to_bf16_bits(eB + oB) | (f32_to_bf16_bits(eD + oD) << 16);
        de[u]  = f32_to_bf16_bits(eA - oA) | (f32_to_bf16_bits(eC - oC) << 16);
        do_[u] = f32_to_bf16_bits(eB - oB) | (f32_to_bf16_bits(eD - oD) << 16);
    }
    const size_t rs = (size_t)m * 2048 + (c0 >> 1);
    const size_t rd = (size_t)(4095 - m) * 2048 + (c0 >> 1);
    *(uint4*)(Te + rs) = make_uint4(se[0], se[1], se[2], se[3]);
    *(uint4*)(To + rs) = make_uint4(so_[0], so_[1], so_[2], so_[3]);
    *(uint4*)(Te + rd) = make_uint4(de[0], de[1], de[2], de[3]);
    *(uint4*)(To + rd) = make_uint4(do_[0], do_[1], do_[2], do_[3]);
}

// ---------------------------------------------------------------------------
// Butterfly 2: Ce2,Co2 [2048][4096] bf16 -> out [4096][4096] f32. (unchanged)
// ---------------------------------------------------------------------------
__global__ void bfly2_kernel(const unsigned short* __restrict__ Ce,
                             const unsigned short* __restrict__ Co,
                             float* __restrict__ out) {
    const int m  = blockIdx.x;
    const int c0 = threadIdx.x << 4;
    const uint4 e0 = *(const uint4*)(Ce + (size_t)m * 4096 + c0);
    const uint4 e1 = *(const uint4*)(Ce + (size_t)m * 4096 + c0 + 8);
    const uint4 o0 = *(const uint4*)(Co + (size_t)m * 4096 + c0);
    const uint4 o1 = *(const uint4*)(Co + (size_t)m * 4096 + c0 + 8);
    const uint32_t eu[8] = {e0.x, e0.y, e0.z, e0.w, e1.x, e1.y, e1.z, e1.w};
    const uint32_t ou[8] = {o0.x, o0.y, o0.z, o0.w, o1.x, o1.y, o1.z, o1.w};
    float s[16], d[16];
#pragma unroll
    for (int u = 0; u < 8; ++u) {
        const float eL = bf16_bits_to_f32(eu[u] & 0xFFFF), oL = bf16_bits_to_f32(ou[u] & 0xFFFF);
        const float eH = bf16_bits_to_f32(eu[u] >> 16),    oH = bf16_bits_to_f32(ou[u] >> 16);
        s[2*u] = eL + oL; s[2*u+1] = eH + oH;
        d[2*u] = eL - oL; d[2*u+1] = eH - oH;
    }
    float* ps = out + (size_t)m * 4096 + c0;
    float* pd = out + (size_t)(4095 - m) * 4096 + c0;
#pragma unroll
    for (int u = 0; u < 4; ++u) {
        *(float4*)(ps + 4 * u) = make_float4(s[4*u], s[4*u+1], s[4*u+2], s[4*u+3]);
        *(float4*)(pd + 4 * u) = make_float4(d[4*u], d[4*u+1], d[4*u+2], d[4*u+3]);
    }
}

// ---------------------------------------------------------------------------
// Pipeline (unchanged from rounds 3/4):
//   prep -> gemm1 (z-parity) -> bfly1 -> gemm2 -> bfly2
// ws (80 MB): Ae[0,8) Ao[8,16) | Xe[16,32) Xo[32,48) (reused as Te,To)
//             | C1e[48,64) C1o[64,80) (reused as C2e,C2o)
// ---------------------------------------------------------------------------
extern "C" void kernel_launch(void* const* d_in, const int* in_sizes, int n_in,
                              void* d_out, int out_size, void* d_ws, size_t ws_size,
                              hipStream_t stream) {
    const float* x = (const float*)d_in[0];
    char* ws = (char*)d_ws;
    const size_t MB = 1024 * 1024;
    unsigned short* Ae = (unsigned short*)(ws);
    unsigned short* Ao = (unsigned short*)(ws + 8 * MB);
    unsigned short* Xe = (unsigned short*)(ws + 16 * MB);   // later Te
    unsigned short* Xo = (unsigned short*)(ws + 32 * MB);   // later To
    unsigned short* C1e = (unsigned short*)(ws + 48 * MB);  // later C2e
    unsigned short* C1o = (unsigned short*)(ws + 64 * MB);  // later C2o
    float* out = (float*)d_out;

    prep_kernel<<<12288, 256, 0, stream>>>(x, Ae, Ao, Xe, Xo);

    dim3 ggrid(16, 8, 2);
    gemm256_kernel<<<ggrid, 512, 0, stream>>>(Ae, Ao, Xe, Xo, C1e, C1o);
    bfly1_kernel<<<2048, 256, 0, stream>>>(C1e, C1o, /*Te=*/Xe, /*To=*/Xo);
    gemm256_kernel<<<ggrid, 512, 0, stream>>>(Ae, Ao, /*Te=*/Xe, /*To=*/Xo, C1e, C1o);
    bfly2_kernel<<<2048, 256, 0, stream>>>(C1e, C1o, out);
}